// Round 3
// baseline (291.300 us; speedup 1.0000x reference)
//
#include <hip/hip_runtime.h>
#include <math.h>

#define DD 32
#define MM 16
#define TROW 80   // tbl row: t[32] | it[32] | cj[8] | pad[8]  (320B = 5 full cache lines)

typedef int          vi4 __attribute__((ext_vector_type(4)));

__device__ __forceinline__ void load8f4(const float* __restrict__ p, float* r) {
    const float4* q = (const float4*)p;
#pragma unroll
    for (int i = 0; i < 8; ++i) {
        float4 v = q[i];
        r[4*i+0] = v.x; r[4*i+1] = v.y; r[4*i+2] = v.z; r[4*i+3] = v.w;
    }
}

// One thread per (item, dim). All register-array indices compile-time (rule #20).
// tbl[i*80 + 0..31]  = t_i[d] = sum_e W_bil[d][e] * item_e[i][e]
// tbl[i*80 + 32..63] = item_e[i][d]
// tbl[i*80 + 64..71] = c_i[j] = sum_d W1[j][64+d] * item_e[i][d]
__global__ void precompute_item(const float* __restrict__ item_table,
                                const float* __restrict__ W_bil,
                                const float* __restrict__ W1,
                                float* __restrict__ tbl, int NI) {
    int g = blockIdx.x * blockDim.x + threadIdx.x;
    if (g >= NI * DD) return;
    int i = g >> 5;
    int d = g & (DD - 1);
    const float* row = item_table + (size_t)i * DD;
    float it[DD];
    load8f4(row, it);   // same-address across the 32 lanes of one item -> broadcast
    const float* w = W_bil + d * DD;
    float s0 = 0.f, s1 = 0.f, s2 = 0.f, s3 = 0.f;
#pragma unroll
    for (int e = 0; e < DD; e += 4) {
        s0 = fmaf(w[e+0], it[e+0], s0);
        s1 = fmaf(w[e+1], it[e+1], s1);
        s2 = fmaf(w[e+2], it[e+2], s2);
        s3 = fmaf(w[e+3], it[e+3], s3);
    }
    float* o = tbl + (size_t)i * TROW;
    o[d]      = (s0 + s1) + (s2 + s3);
    o[DD + d] = row[d];            // direct global re-load (L1 hit), NOT it[d]
    if (d < 8) {
        const float* w1 = W1 + d * 96 + 64;
        float c0 = 0.f, c1 = 0.f, c2 = 0.f, c3 = 0.f;
#pragma unroll
        for (int e = 0; e < DD; e += 4) {
            c0 = fmaf(w1[e+0], it[e+0], c0);
            c1 = fmaf(w1[e+1], it[e+1], c1);
            c2 = fmaf(w1[e+2], it[e+2], c2);
            c3 = fmaf(w1[e+3], it[e+3], c3);
        }
        o[64 + d] = (c0 + c1) + (c2 + c3);
    }
}

// Member-parallel main: 4 threads per group-item pair b. Thread q = tid&3 owns
// member slots q*4..q*4+3 (mask is a prefix, so my active count = popc of my
// 4 mask bytes). All 4 slots are branch-free: masked slots re-load slot-0's id
// (valid user id, L1-hot) and gate the score to 0. Partial fin combined across
// the 4 lanes by shfl_xor butterfly; MLP split 2 h_j per lane.
template <bool USE_TBL>
__global__ __launch_bounds__(256)
void bilinear_main(const int* __restrict__ item_inputs,
                   const int* __restrict__ member_ids,
                   const unsigned char* __restrict__ member_mask,
                   const float* __restrict__ user_table,
                   const float* __restrict__ item_table,
                   const float* __restrict__ tbl,
                   const float* __restrict__ W_bil,
                   const float* __restrict__ b_bil,
                   const float* __restrict__ W1,
                   const float* __restrict__ b1v,
                   const float* __restrict__ W2,
                   const float* __restrict__ b2v,
                   float* __restrict__ out, int Btot) {
    int tid = blockIdx.x * blockDim.x + threadIdx.x;
    int b = tid >> 2;
    int q = tid & 3;
    if (b >= Btot) return;

    // One-touch streams, all perfectly coalesced at this decomposition:
    // ids: 16B/lane contiguous; mask: 4B/lane contiguous.
    int item = __builtin_nontemporal_load(item_inputs + b);
    unsigned mw = __builtin_nontemporal_load((const unsigned*)member_mask + tid);
    int cnt = __popc(mw & 0x01010101u);     // active members in MY 4 slots
    vi4 idv = __builtin_nontemporal_load((const vi4*)member_ids + tid);
    int id0 = idv[0];

    // t row (4 lanes same address -> one L1 request).
    float t[DD];
    const float* tb = nullptr;
    if (USE_TBL) {
        tb = tbl + (size_t)item * TROW;
        load8f4(tb, t);
    } else {
        float it0[DD];
        load8f4(item_table + (size_t)item * DD, it0);
#pragma unroll 4
        for (int d = 0; d < DD; ++d) {
            float s = 0.f;
#pragma unroll
            for (int e = 0; e < DD; ++e) s = fmaf(W_bil[d * DD + e], it0[e], s);
            t[d] = s;
        }
    }

    float bb = b_bil[0];
    float fin[DD];
#pragma unroll
    for (int d = 0; d < DD; ++d) fin[d] = 0.f;

    // 4 static member slots, straight-line (compiler free to pipeline loads).
#pragma unroll
    for (int k = 0; k < 4; ++k) {
        bool act = (k < cnt);
        int idk = act ? idv[k] : id0;
        float me[DD];
        load8f4(user_table + (size_t)idk * DD, me);
        float s0 = 0.f, s1 = 0.f, s2 = 0.f, s3 = 0.f;
#pragma unroll
        for (int d = 0; d < DD; d += 4) {
            s0 = fmaf(me[d+0], t[d+0], s0);
            s1 = fmaf(me[d+1], t[d+1], s1);
            s2 = fmaf(me[d+2], t[d+2], s2);
            s3 = fmaf(me[d+3], t[d+3], s3);
        }
        float s = act ? (((s0 + s1) + (s2 + s3)) + bb) : 0.f;
#pragma unroll
        for (int d = 0; d < DD; ++d) fin[d] = fmaf(s, me[d], fin[d]);
    }

    // Combine partial fin across the 4 lanes of this group (exact: addition order
    // per dim is a fixed tree).
#pragma unroll
    for (int d = 0; d < DD; ++d) fin[d] += __shfl_xor(fin[d], 1);
#pragma unroll
    for (int d = 0; d < DD; ++d) fin[d] += __shfl_xor(fin[d], 2);

    // Epilogue: lane q computes h_{2q}, h_{2q+1}.
    float it[DD];
    load8f4(USE_TBL ? (tb + DD) : (item_table + (size_t)item * DD), it);

    int j0 = 2 * q;
    float c0, c1;
    if (USE_TBL) {
        c0 = tb[64 + j0];
        c1 = tb[64 + j0 + 1];
    } else {
        float a0 = 0.f, a1 = 0.f;
#pragma unroll
        for (int d = 0; d < DD; ++d) {
            a0 = fmaf(W1[j0 * 96 + 64 + d], it[d], a0);
            a1 = fmaf(W1[(j0 + 1) * 96 + 64 + d], it[d], a1);
        }
        c0 = a0; c1 = a1;
    }
    float h0 = c0 + b1v[j0];
    float h1 = c1 + b1v[j0 + 1];

    const float4* w1r0a = (const float4*)(W1 + j0 * 96);         // W1[j0, 0..31]
    const float4* w1r0b = (const float4*)(W1 + j0 * 96 + 32);    // W1[j0, 32..63]
    const float4* w1r1a = (const float4*)(W1 + (j0 + 1) * 96);
    const float4* w1r1b = (const float4*)(W1 + (j0 + 1) * 96 + 32);
#pragma unroll
    for (int dq = 0; dq < 8; ++dq) {
        float4 wa0 = w1r0a[dq], wb0 = w1r0b[dq];
        float4 wa1 = w1r1a[dq], wb1 = w1r1b[dq];
        float f0 = fin[4*dq+0], f1 = fin[4*dq+1], f2 = fin[4*dq+2], f3 = fin[4*dq+3];
        float p0 = f0 * it[4*dq+0], p1 = f1 * it[4*dq+1];
        float p2 = f2 * it[4*dq+2], p3 = f3 * it[4*dq+3];
        h0 = fmaf(wa0.x, p0, h0); h0 = fmaf(wb0.x, f0, h0);
        h0 = fmaf(wa0.y, p1, h0); h0 = fmaf(wb0.y, f1, h0);
        h0 = fmaf(wa0.z, p2, h0); h0 = fmaf(wb0.z, f2, h0);
        h0 = fmaf(wa0.w, p3, h0); h0 = fmaf(wb0.w, f3, h0);
        h1 = fmaf(wa1.x, p0, h1); h1 = fmaf(wb1.x, f0, h1);
        h1 = fmaf(wa1.y, p1, h1); h1 = fmaf(wb1.y, f1, h1);
        h1 = fmaf(wa1.z, p2, h1); h1 = fmaf(wb1.z, f2, h1);
        h1 = fmaf(wa1.w, p3, h1); h1 = fmaf(wb1.w, f3, h1);
    }
    float hv0 = h0 > 0.f ? h0 : 0.f;
    float hv1 = h1 > 0.f ? h1 : 0.f;
    float zp = W2[j0] * hv0 + W2[j0 + 1] * hv1;
    zp += __shfl_xor(zp, 1);
    zp += __shfl_xor(zp, 2);
    if (q == 0) {
        float z = zp + b2v[0];
        __builtin_nontemporal_store(1.f / (1.f + __expf(-z)), out + b);
    }
}

extern "C" void kernel_launch(void* const* d_in, const int* in_sizes, int n_in,
                              void* d_out, int out_size, void* d_ws, size_t ws_size,
                              hipStream_t stream) {
    const int*           item_inputs = (const int*)d_in[0];
    const int*           member_ids  = (const int*)d_in[1];
    const unsigned char* member_mask = (const unsigned char*)d_in[2];
    const float*         user_table  = (const float*)d_in[3];
    const float*         item_table  = (const float*)d_in[4];
    const float*         W_bil       = (const float*)d_in[5];
    const float*         b_bil       = (const float*)d_in[6];
    const float*         W1          = (const float*)d_in[7];
    const float*         b1          = (const float*)d_in[8];
    const float*         W2          = (const float*)d_in[9];
    const float*         b2          = (const float*)d_in[10];
    float* out = (float*)d_out;

    int Btot = in_sizes[0];
    int NI   = in_sizes[4] / DD;

    bool use_tbl = ws_size >= (size_t)NI * TROW * sizeof(float);
    int blk = 256;
    int nthreads = Btot * 4;
    if (use_tbl) {
        float* tbl = (float*)d_ws;
        precompute_item<<<(NI * DD + blk - 1) / blk, blk, 0, stream>>>(item_table, W_bil, W1, tbl, NI);
        bilinear_main<true><<<(nthreads + blk - 1) / blk, blk, 0, stream>>>(
            item_inputs, member_ids, member_mask, user_table, item_table, tbl,
            W_bil, b_bil, W1, b1, W2, b2, out, Btot);
    } else {
        bilinear_main<false><<<(nthreads + blk - 1) / blk, blk, 0, stream>>>(
            item_inputs, member_ids, member_mask, user_table, item_table, nullptr,
            W_bil, b_bil, W1, b1, W2, b2, out, Btot);
    }
}

// Round 4
// 154.625 us; speedup vs baseline: 1.8839x; 1.8839x over previous
//
#include <hip/hip_runtime.h>
#include <math.h>

#define DD 32
#define MM 16
#define TROW 40   // tbl row: t[32] | cj[8]  (round-0 proven layout)

__device__ __forceinline__ void load8f4(const float* __restrict__ p, float* r) {
    const float4* q = (const float4*)p;
#pragma unroll
    for (int i = 0; i < 8; ++i) {
        float4 v = q[i];
        r[4*i+0] = v.x; r[4*i+1] = v.y; r[4*i+2] = v.z; r[4*i+3] = v.w;
    }
}

// Round-0 exact precompute (measured fast there): one thread per item.
// tbl[i*40 + 0..31] = t_i[d] = sum_e W_bil[d][e] * item_e[i][e]
// tbl[i*40 + 32..39] = c_i[j] = sum_d W1[j][64+d] * item_e[i][d]
__global__ void precompute_item(const float* __restrict__ item_table,
                                const float* __restrict__ W_bil,
                                const float* __restrict__ W1,
                                float* __restrict__ tbl, int NI) {
    int i = blockIdx.x * blockDim.x + threadIdx.x;
    if (i >= NI) return;
    float it[DD];
    load8f4(item_table + (size_t)i * DD, it);
    float* o = tbl + (size_t)i * TROW;
#pragma unroll 4
    for (int d = 0; d < DD; ++d) {
        float s = 0.f;
#pragma unroll
        for (int e = 0; e < DD; ++e) s = fmaf(W_bil[d * DD + e], it[e], s);
        o[d] = s;
    }
#pragma unroll
    for (int j = 0; j < 8; ++j) {
        float s = 0.f;
#pragma unroll
        for (int d = 0; d < DD; ++d) s = fmaf(W1[j * 96 + 64 + d], it[d], s);
        o[32 + j] = s;
    }
}

// Quad-cooperative main: 4 lanes per group b; lane q owns dims q*8..q*8+7.
// Per member the quad loads one 128B row CONTIGUOUSLY (32B/lane) -> 16 distinct
// cache lines per wave-instruction instead of 64. Member loop is len-gated
// (len uniform within the quad -> no intra-quad divergence). Score = in-quad
// shfl_xor tree; fin stays distributed (8 floats/lane); MLP partials combined
// the same way. ~60 VGPR -> high residency; grid = 4*B threads.
template <bool USE_TBL>
__global__ __launch_bounds__(256)
void bilinear_main(const int* __restrict__ item_inputs,
                   const int* __restrict__ member_ids,
                   const unsigned char* __restrict__ member_mask,
                   const float* __restrict__ user_table,
                   const float* __restrict__ item_table,
                   const float* __restrict__ tbl,
                   const float* __restrict__ W_bil,
                   const float* __restrict__ b_bil,
                   const float* __restrict__ W1,
                   const float* __restrict__ b1v,
                   const float* __restrict__ W2,
                   const float* __restrict__ b2v,
                   float* __restrict__ out, int Btot) {
    int tid = blockIdx.x * blockDim.x + threadIdx.x;
    int b = tid >> 2;
    if (b >= Btot) return;
    int q  = tid & 3;
    int ko = q * 8;                              // my dim-slice offset

    int item = item_inputs[b];                   // same addr across quad

    // len: 16B mask row, same-addr broadcast within quad (prefix mask).
    const uint4 mv = *(const uint4*)(member_mask + (size_t)b * MM);
    int len = __popc(mv.x & 0x01010101u) + __popc(mv.y & 0x01010101u) +
              __popc(mv.z & 0x01010101u) + __popc(mv.w & 0x01010101u);

    // My 8-float slice of t.
    float t[8];
    if (USE_TBL) {
        const float4* tp = (const float4*)(tbl + (size_t)item * TROW + ko);
        float4 a = tp[0], c = tp[1];
        t[0]=a.x; t[1]=a.y; t[2]=a.z; t[3]=a.w; t[4]=c.x; t[5]=c.y; t[6]=c.z; t[7]=c.w;
    } else {
        float itf[DD];
        load8f4(item_table + (size_t)item * DD, itf);
#pragma unroll
        for (int k = 0; k < 8; ++k) {
            const float* w = W_bil + (ko + k) * DD;
            float s0 = 0.f, s1 = 0.f, s2 = 0.f, s3 = 0.f;
#pragma unroll
            for (int e = 0; e < DD; e += 4) {
                s0 = fmaf(w[e+0], itf[e+0], s0);
                s1 = fmaf(w[e+1], itf[e+1], s1);
                s2 = fmaf(w[e+2], itf[e+2], s2);
                s3 = fmaf(w[e+3], itf[e+3], s3);
            }
            t[k] = (s0 + s1) + (s2 + s3);
        }
    }

    float bb = b_bil[0];
    float fin[8];
#pragma unroll
    for (int k = 0; k < 8; ++k) fin[k] = 0.f;

    const int* idp = member_ids + (size_t)b * MM;
    int id = idp[0];
    for (int m = 0; m < len; ++m) {
        int idn = idp[(m + 1) & (MM - 1)];       // prefetch next id (clamped/wrapped, always valid)
        const float4* up = (const float4*)(user_table + (size_t)id * DD + ko);
        float4 a = up[0], c = up[1];
        float me0 = a.x, me1 = a.y, me2 = a.z, me3 = a.w;
        float me4 = c.x, me5 = c.y, me6 = c.z, me7 = c.w;
        float s0 = fmaf(me0, t[0], fmaf(me1, t[1], 0.f));
        float s1 = fmaf(me2, t[2], fmaf(me3, t[3], 0.f));
        float s2 = fmaf(me4, t[4], fmaf(me5, t[5], 0.f));
        float s3 = fmaf(me6, t[6], fmaf(me7, t[7], 0.f));
        float s = (s0 + s1) + (s2 + s3);
        s += __shfl_xor(s, 1);                   // in-quad combine (lanes uniformly active)
        s += __shfl_xor(s, 2);
        s += bb;
        fin[0] = fmaf(s, me0, fin[0]); fin[1] = fmaf(s, me1, fin[1]);
        fin[2] = fmaf(s, me2, fin[2]); fin[3] = fmaf(s, me3, fin[3]);
        fin[4] = fmaf(s, me4, fin[4]); fin[5] = fmaf(s, me5, fin[5]);
        fin[6] = fmaf(s, me6, fin[6]); fin[7] = fmaf(s, me7, fin[7]);
        id = idn;
    }

    // it slice (quad-contiguous 128B from item_table).
    const float4* ip = (const float4*)(item_table + (size_t)item * DD + ko);
    float4 ia = ip[0], ic = ip[1];
    float it8[8] = {ia.x, ia.y, ia.z, ia.w, ic.x, ic.y, ic.z, ic.w};

    float p8[8];
#pragma unroll
    for (int k = 0; k < 8; ++k) p8[k] = fin[k] * it8[k];

    // Per-lane partial of h_j over my 8 dims (both streams), all 8 j.
    float u[8];
#pragma unroll
    for (int j = 0; j < 8; ++j) {
        const float* wr = W1 + j * 96 + ko;
        float4 wa0 = *(const float4*)(wr);
        float4 wa1 = *(const float4*)(wr + 4);
        float4 wb0 = *(const float4*)(wr + 32);
        float4 wb1 = *(const float4*)(wr + 36);
        float x = 0.f, y = 0.f;
        x = fmaf(wa0.x, p8[0], x); y = fmaf(wb0.x, fin[0], y);
        x = fmaf(wa0.y, p8[1], x); y = fmaf(wb0.y, fin[1], y);
        x = fmaf(wa0.z, p8[2], x); y = fmaf(wb0.z, fin[2], y);
        x = fmaf(wa0.w, p8[3], x); y = fmaf(wb0.w, fin[3], y);
        x = fmaf(wa1.x, p8[4], x); y = fmaf(wb1.x, fin[4], y);
        x = fmaf(wa1.y, p8[5], x); y = fmaf(wb1.y, fin[5], y);
        x = fmaf(wa1.z, p8[6], x); y = fmaf(wb1.z, fin[6], y);
        x = fmaf(wa1.w, p8[7], x); y = fmaf(wb1.w, fin[7], y);
        u[j] = x + y;
    }
#pragma unroll
    for (int j = 0; j < 8; ++j) {
        u[j] += __shfl_xor(u[j], 1);
        u[j] += __shfl_xor(u[j], 2);
    }

    if (q == 0) {
        float cj[8];
        if (USE_TBL) {
            const float4* cp = (const float4*)(tbl + (size_t)item * TROW + 32);
            float4 ca = cp[0], cb = cp[1];
            cj[0]=ca.x; cj[1]=ca.y; cj[2]=ca.z; cj[3]=ca.w;
            cj[4]=cb.x; cj[5]=cb.y; cj[6]=cb.z; cj[7]=cb.w;
        } else {
            float itf[DD];
            load8f4(item_table + (size_t)item * DD, itf);
#pragma unroll
            for (int j = 0; j < 8; ++j) {
                float s = 0.f;
#pragma unroll
                for (int d = 0; d < DD; ++d) s = fmaf(W1[j * 96 + 64 + d], itf[d], s);
                cj[j] = s;
            }
        }
        float z = b2v[0];
#pragma unroll
        for (int j = 0; j < 8; ++j) {
            float hv = u[j] + cj[j] + b1v[j];
            hv = hv > 0.f ? hv : 0.f;
            z = fmaf(W2[j], hv, z);
        }
        __builtin_nontemporal_store(1.f / (1.f + __expf(-z)), out + b);
    }
}

extern "C" void kernel_launch(void* const* d_in, const int* in_sizes, int n_in,
                              void* d_out, int out_size, void* d_ws, size_t ws_size,
                              hipStream_t stream) {
    const int*           item_inputs = (const int*)d_in[0];
    const int*           member_ids  = (const int*)d_in[1];
    const unsigned char* member_mask = (const unsigned char*)d_in[2];
    const float*         user_table  = (const float*)d_in[3];
    const float*         item_table  = (const float*)d_in[4];
    const float*         W_bil       = (const float*)d_in[5];
    const float*         b_bil       = (const float*)d_in[6];
    const float*         W1          = (const float*)d_in[7];
    const float*         b1          = (const float*)d_in[8];
    const float*         W2          = (const float*)d_in[9];
    const float*         b2          = (const float*)d_in[10];
    float* out = (float*)d_out;

    int Btot = in_sizes[0];
    int NI   = in_sizes[4] / DD;

    bool use_tbl = ws_size >= (size_t)NI * TROW * sizeof(float);
    int blk = 256;
    long long nthreads = (long long)Btot * 4;
    if (use_tbl) {
        float* tbl = (float*)d_ws;
        precompute_item<<<(NI + blk - 1) / blk, blk, 0, stream>>>(item_table, W_bil, W1, tbl, NI);
        bilinear_main<true><<<(int)((nthreads + blk - 1) / blk), blk, 0, stream>>>(
            item_inputs, member_ids, member_mask, user_table, item_table, tbl,
            W_bil, b_bil, W1, b1, W2, b2, out, Btot);
    } else {
        bilinear_main<false><<<(int)((nthreads + blk - 1) / blk), blk, 0, stream>>>(
            item_inputs, member_ids, member_mask, user_table, item_table, nullptr,
            W_bil, b_bil, W1, b1, W2, b2, out, Btot);
    }
}